// Round 3
// baseline (282.529 us; speedup 1.0000x reference)
//
#include <hip/hip_runtime.h>
#include <hip/hip_cooperative_groups.h>
#include <math.h>

namespace cg = cooperative_groups;

// Problem constants (B=1, C=256, T=8, H=32, W=32, L=4, NUM_PTS=4, N_OFF=4)
#define CDIM 256
#define TDIM 8
#define HDIM 32
#define WDIM 32
#define LDIM 4
#define THW 8192
#define CSTR 32768            // T*H*W*L, per-channel stride in features
#define NS 64                 // NUM_PTS^3
#define OUT0_SIZE 8388608     // C*T*H*W*L

// uniform_flat_indices axes for T=8 / H=W=32, n=4 (round(linspace(hop/2, D-1-hop/2, 4)))
__device__ __constant__ int c_ti[4] = {1, 3, 4, 6};
__device__ __constant__ int c_hw[4] = {4, 12, 19, 27};

__device__ __forceinline__ float sigm(float x) { return 1.f / (1.f + expf(-x)); }

__device__ __forceinline__ float wave_sum64(float x) {
#pragma unroll
    for (int s = 32; s > 0; s >>= 1) x += __shfl_xor(x, s, 64);
    return x;
}

__global__ void __launch_bounds__(256, 1)
k_fused(const float* __restrict__ feat, const float* __restrict__ pos,
        const float* __restrict__ W1, const float* __restrict__ b1,
        const float* __restrict__ W2, const float* __restrict__ b2,
        const float* __restrict__ Wn, const float* __restrict__ bn,
        const float* __restrict__ Woff, const float* __restrict__ boff,
        const float* __restrict__ Ww, const float* __restrict__ bw,
        const float* __restrict__ gamma, const float* __restrict__ beta,
        float* __restrict__ out, float* __restrict__ glob,
        float* __restrict__ p1, float* __restrict__ p2,
        float* __restrict__ next_out) {
    cg::grid_group grid = cg::this_grid();
    const int tid = threadIdx.x;
    const int b = blockIdx.x;

    __shared__ float4 sred[256];
    __shared__ float sA[16][48];
    __shared__ float sH[16][16];
    __shared__ float s_samp[4][3];
    __shared__ float s_wo[4];
    __shared__ float s_w[32];
    __shared__ int   s_o[32];
    __shared__ float red1[4], red2[4], redn[3][4];

    // ================= P1: fill output0 with beta[c]; glob[l][c] = mean =================
    {
        int c = b;
        float bv = beta[c];
        float4 bf = make_float4(bv, bv, bv, bv);
        const float4* f = (const float4*)(feat + (size_t)c * CSTR);
        float4* o = (float4*)(out + (size_t)c * CSTR);
        float4 a = make_float4(0.f, 0.f, 0.f, 0.f);
        for (int i = tid; i < THW; i += 256) {
            float4 v = f[i];
            o[i] = bf;
            a.x += v.x; a.y += v.y; a.z += v.z; a.w += v.w;
        }
        sred[tid] = a;
        __syncthreads();
        for (int off = 128; off > 0; off >>= 1) {
            if (tid < off) {
                float4 t = sred[tid + off];
                sred[tid].x += t.x; sred[tid].y += t.y;
                sred[tid].z += t.z; sred[tid].w += t.w;
            }
            __syncthreads();
        }
        if (tid == 0) {
            float4 t = sred[0];
            glob[0 * CDIM + c] = t.x * (1.f / 8192.f);
            glob[1 * CDIM + c] = t.y * (1.f / 8192.f);
            glob[2 * CDIM + c] = t.z * (1.f / 8192.f);
            glob[3 * CDIM + c] = t.w * (1.f / 8192.f);
        }
    }
    grid.sync();

    // ================= P2: GEMM1 (K=768, split-K 16x48) with inline gather =================
    {
        int mt = b >> 4, ks = b & 15;
        for (int v = tid; v < 768; v += 256) {
            int i = v / 48, kk = v - i * 48;
            int k = ks * 48 + kk;
            int m = mt * 16 + i, l = m >> 6, n = m & 63;
            int sp = (c_ti[n >> 4] * HDIM + c_hw[(n >> 2) & 3]) * WDIM + c_hw[n & 3];
            float val;
            if (k < 256)      val = feat[(size_t)k * CSTR + sp * LDIM + l];
            else if (k < 512) val = pos[(size_t)(k - 256) * CSTR + sp * LDIM + l];
            else              val = glob[l * CDIM + (k - 512)];
            sA[i][kk] = val;
        }
        __syncthreads();
        int j = tid;
        float acc[16];
#pragma unroll
        for (int i = 0; i < 16; ++i) acc[i] = 0.f;
#pragma unroll 4
        for (int kk = 0; kk < 48; ++kk) {
            float wv = W1[(size_t)(ks * 48 + kk) * 256 + j];
#pragma unroll
            for (int i = 0; i < 16; ++i) acc[i] = fmaf(sA[i][kk], wv, acc[i]);
        }
#pragma unroll
        for (int i = 0; i < 16; ++i)
            p1[((size_t)(ks * 256 + mt * 16 + i)) * 256 + j] = acc[i];
    }
    grid.sync();

    // ================= P3: h1 chunk reduce + GEMM2 (K=256, split-K 16x16) =================
    {
        int mt = b >> 4, ks = b & 15;
        {
            int i = tid >> 4, kk = tid & 15;
            int m = mt * 16 + i, k = ks * 16 + kk;
            float v = b1[k];
#pragma unroll
            for (int s = 0; s < 16; ++s) v += p1[((size_t)(s * 256 + m)) * 256 + k];
            sH[i][kk] = fmaxf(v, 0.f);
        }
        __syncthreads();
        int j = tid;
        float acc[16];
#pragma unroll
        for (int i = 0; i < 16; ++i) acc[i] = 0.f;
#pragma unroll
        for (int kk = 0; kk < 16; ++kk) {
            float wv = W2[(size_t)(ks * 16 + kk) * 256 + j];
#pragma unroll
            for (int i = 0; i < 16; ++i) acc[i] = fmaf(sH[i][kk], wv, acc[i]);
        }
#pragma unroll
        for (int i = 0; i < 16; ++i)
            p2[((size_t)(ks * 256 + mt * 16 + i)) * 256 + j] = acc[i];
    }
    grid.sync();

    // ================= P4: heads + trilinear sample + LayerNorm + scatter-write =================
    {
        int m = b, l = m >> 6, n = m & 63;
        int j = tid, o = j >> 6, r = j & 63;

        float v = b2[j];
#pragma unroll
        for (int s = 0; s < 16; ++s) v += p2[((size_t)(s * 256 + m)) * 256 + j];
        v = fmaxf(v, 0.f);              // osrc[m][j]

        // nxt = osrc @ Wn (full-256 reduction via per-wave partials)
        float pn0 = wave_sum64(v * Wn[j * 3 + 0]);
        float pn1 = wave_sum64(v * Wn[j * 3 + 1]);
        float pn2 = wave_sum64(v * Wn[j * 3 + 2]);
        if (r == 0) { redn[0][o] = pn0; redn[1][o] = pn1; redn[2][o] = pn2; }

        // per-o heads (d=64): offset and w_o
        float po0 = wave_sum64(v * Woff[r * 3 + 0]);
        float po1 = wave_sum64(v * Woff[r * 3 + 1]);
        float po2 = wave_sum64(v * Woff[r * 3 + 2]);
        float z0  = wave_sum64(v * Ww[r * 2 + 0]);
        float z1  = wave_sum64(v * Ww[r * 2 + 1]);

        float tn = (float)c_ti[n >> 4] / 7.f;
        float hn = (float)c_hw[(n >> 2) & 3] / 31.f;
        float wn = (float)c_hw[n & 3] / 31.f;
        float lg0 = logf(tn / (1.f - tn));
        float lg1 = logf(hn / (1.f - hn));
        float lg2 = logf(wn / (1.f - wn));

        if (r == 0) {
            s_samp[o][0] = sigm(lg0 + po0 + boff[0]) * 2.f - 1.f;
            s_samp[o][1] = sigm(lg1 + po1 + boff[1]) * 2.f - 1.f;
            s_samp[o][2] = sigm(lg2 + po2 + boff[2]) * 2.f - 1.f;
            s_wo[o] = 1.f / (1.f + expf((z0 + bw[0]) - (z1 + bw[1])));   // softmax[...,1]
        }
        __syncthreads();

        if (tid == 0) {
            float t0 = redn[0][0] + redn[0][1] + redn[0][2] + redn[0][3];
            float t1 = redn[1][0] + redn[1][1] + redn[1][2] + redn[1][3];
            float t2 = redn[2][0] + redn[2][1] + redn[2][2] + redn[2][3];
            float d0 = rintf(sigm(lg0 + t0 + bn[0]) * 7.f);
            float d1 = rintf(sigm(lg1 + t1 + bn[1]) * 31.f);
            float d2 = rintf(sigm(lg2 + t2 + bn[2]) * 31.f);
            next_out[m] = 1024.f * d0 + 32.f * d1 + d2;   // H*W*d0 + W*d1 + d2
        }

        if (tid < 4) {
            int oo = tid;
            float wv = s_wo[oo];
            float g0 = s_samp[oo][0], g1 = s_samp[oo][1], g2 = s_samp[oo][2];
            // reference grid_sample: ch0 -> x over W, ch1 -> y over H, ch2 -> z over D(=T)
            float ix = ((g0 + 1.f) * 32.f - 1.f) * 0.5f;
            float iy = ((g1 + 1.f) * 32.f - 1.f) * 0.5f;
            float iz = ((g2 + 1.f) * 8.f  - 1.f) * 0.5f;
            float x0f = floorf(ix), y0f = floorf(iy), z0f = floorf(iz);
            float fx = ix - x0f, fy = iy - y0f, fz = iz - z0f;
            int x0 = (int)x0f, y0 = (int)y0f, z0 = (int)z0f;
#pragma unroll
            for (int k = 0; k < 8; ++k) {
                int dx = k & 1, dy = (k >> 1) & 1, dz = k >> 2;
                int xi = x0 + dx, yi = y0 + dy, zi = z0 + dz;
                float w = (dx ? fx : 1.f - fx) * (dy ? fy : 1.f - fy) * (dz ? fz : 1.f - fz);
                bool valid = (xi >= 0) && (xi < WDIM) && (yi >= 0) && (yi < HDIM) && (zi >= 0) && (zi < TDIM);
                int xc = min(max(xi, 0), WDIM - 1);
                int yc = min(max(yi, 0), HDIM - 1);
                int zc = min(max(zi, 0), TDIM - 1);
                s_w[oo * 8 + k] = valid ? w * wv : 0.f;
                s_o[oo * 8 + k] = ((zc * HDIM + yc) * WDIM + xc) * LDIM + l;
            }
        }
        __syncthreads();

        int c = tid;
        const float* fc = feat + (size_t)c * CSTR;
        int sp = (c_ti[n >> 4] * HDIM + c_hw[(n >> 2) & 3]) * WDIM + c_hw[n & 3];
        float acc = fc[sp * LDIM + l];          // features + wsf at this site
#pragma unroll
        for (int k = 0; k < 32; ++k) acc += s_w[k] * fc[s_o[k]];

        // LayerNorm over C=256 (one value per thread)
        float s1 = acc, s2 = acc * acc;
#pragma unroll
        for (int d = 32; d > 0; d >>= 1) { s1 += __shfl_xor(s1, d, 64); s2 += __shfl_xor(s2, d, 64); }
        int wid = tid >> 6;
        if ((tid & 63) == 0) { red1[wid] = s1; red2[wid] = s2; }
        __syncthreads();
        float tot  = red1[0] + red1[1] + red1[2] + red1[3];
        float totq = red2[0] + red2[1] + red2[2] + red2[3];
        float mu = tot * (1.f / 256.f);
        float var = fmaxf(totq * (1.f / 256.f) - mu * mu, 0.f);
        float y = (acc - mu) * rsqrtf(var + 1e-5f) * gamma[c] + beta[c];
        out[(size_t)c * CSTR + sp * LDIM + l] = y;
    }
}

extern "C" void kernel_launch(void* const* d_in, const int* in_sizes, int n_in,
                              void* d_out, int out_size, void* d_ws, size_t ws_size,
                              hipStream_t stream) {
    const float* feat = (const float*)d_in[0];
    const float* pos  = (const float*)d_in[1];
    const float* W1   = (const float*)d_in[2];
    const float* b1   = (const float*)d_in[3];
    const float* W2   = (const float*)d_in[4];
    const float* b2   = (const float*)d_in[5];
    const float* Wn   = (const float*)d_in[6];
    const float* bn   = (const float*)d_in[7];
    // d_in[8]=Wl, d_in[9]=bl provably unused (softmax rows sum to 1)
    const float* Woff = (const float*)d_in[10];
    const float* boff = (const float*)d_in[11];
    const float* Ww   = (const float*)d_in[12];
    const float* bw   = (const float*)d_in[13];
    const float* gamma= (const float*)d_in[14];
    const float* beta = (const float*)d_in[15];
    float* out = (float*)d_out;
    float* next_out = out + OUT0_SIZE;

    float* ws   = (float*)d_ws;
    float* glob = ws;                       // 1024
    float* p1   = glob + 1024;              // 16*256*256 = 1048576
    float* p2   = p1 + 1048576;             // 1048576

    void* args[] = {
        (void*)&feat, (void*)&pos, (void*)&W1, (void*)&b1, (void*)&W2, (void*)&b2,
        (void*)&Wn, (void*)&bn, (void*)&Woff, (void*)&boff, (void*)&Ww, (void*)&bw,
        (void*)&gamma, (void*)&beta, (void*)&out, (void*)&glob, (void*)&p1, (void*)&p2,
        (void*)&next_out
    };
    hipLaunchCooperativeKernel((void*)k_fused, dim3(256), dim3(256), args, 0, stream);
}

// Round 4
// 159.488 us; speedup vs baseline: 1.7715x; 1.7715x over previous
//
#include <hip/hip_runtime.h>
#include <math.h>

// Problem constants (B=1, C=256, T=8, H=32, W=32, L=4, NUM_PTS=4, N_OFF=4)
#define CDIM 256
#define TDIM 8
#define HDIM 32
#define WDIM 32
#define LDIM 4
#define THW 8192
#define CSTR 32768            // T*H*W*L, per-channel stride in features
#define NS 64                 // NUM_PTS^3
#define OUT0_SIZE 8388608     // C*T*H*W*L

// GEMM1: K=768, 64 k-splits of 12; 16 m-tiles of 16 rows -> 1024 blocks
#define G1_KS 64
#define G1_KB 12
// GEMM2: K=256, 32 k-splits of 8; 32 m-tiles of 8 rows -> 1024 blocks
#define G2_KS 32
#define G2_KB 8

// uniform_flat_indices axes for T=8 / H=W=32, n=4 (round(linspace(hop/2, D-1-hop/2, 4)))
__device__ __constant__ int c_ti[4] = {1, 3, 4, 6};
__device__ __constant__ int c_hw[4] = {4, 12, 19, 27};

__device__ __forceinline__ float sigm(float x) { return 1.f / (1.f + expf(-x)); }

__device__ __forceinline__ float wave_sum64(float x) {
#pragma unroll
    for (int s = 32; s > 0; s >>= 1) x += __shfl_xor(x, s, 64);
    return x;
}

// ---- 1. Fill out with beta[c] + per-block partial sums of feat (8 blocks per channel) ----
__global__ void k_fill_part(const float* __restrict__ feat, const float* __restrict__ beta,
                            float* __restrict__ out, float4* __restrict__ partF) {
    int c = blockIdx.x >> 3, part = blockIdx.x & 7;
    float bv = beta[c];
    float4 bf = make_float4(bv, bv, bv, bv);
    const float4* f = (const float4*)(feat + (size_t)c * CSTR) + part * 1024;
    float4* o = (float4*)(out + (size_t)c * CSTR) + part * 1024;
    float4 a = make_float4(0.f, 0.f, 0.f, 0.f);
#pragma unroll
    for (int it = 0; it < 4; ++it) {
        int i = it * 256 + threadIdx.x;
        float4 v = f[i];
        o[i] = bf;
        a.x += v.x; a.y += v.y; a.z += v.z; a.w += v.w;
    }
    __shared__ float4 sred[256];
    sred[threadIdx.x] = a;
    __syncthreads();
    for (int off = 128; off > 0; off >>= 1) {
        if (threadIdx.x < off) {
            float4 t = sred[threadIdx.x + off];
            sred[threadIdx.x].x += t.x; sred[threadIdx.x].y += t.y;
            sred[threadIdx.x].z += t.z; sred[threadIdx.x].w += t.w;
        }
        __syncthreads();
    }
    if (threadIdx.x == 0) partF[blockIdx.x] = sred[0];
}

// ---- 2. glob[l][c] = sum of 8 partials / 8192 ----
__global__ void k_globred(const float4* __restrict__ partF, float* __restrict__ glob) {
    int l = blockIdx.x, c = threadIdx.x;
    float s = 0.f;
#pragma unroll
    for (int p = 0; p < 8; ++p) {
        float4 v = partF[c * 8 + p];
        s += (l == 0) ? v.x : (l == 1) ? v.y : (l == 2) ? v.z : v.w;
    }
    glob[l * CDIM + c] = s * (1.f / 8192.f);
}

// ---- 3. GEMM1 partials with inline gather: 1024 blocks = 16 mt x 64 ks ----
__global__ void k_gemm1(const float* __restrict__ feat, const float* __restrict__ pos,
                        const float* __restrict__ glob, const float* __restrict__ W1,
                        float* __restrict__ p1) {
    __shared__ float sA[16][G1_KB];
    int mt = blockIdx.x >> 6, ks = blockIdx.x & 63;
    int k0 = ks * G1_KB;
    int t = threadIdx.x;
    if (t < 16 * G1_KB) {
        int i = t / G1_KB, kk = t - i * G1_KB;
        int k = k0 + kk;
        int m = mt * 16 + i, l = m >> 6, n = m & 63;
        int sp = (c_ti[n >> 4] * HDIM + c_hw[(n >> 2) & 3]) * WDIM + c_hw[n & 3];
        float val;
        if (k < 256)      val = feat[(size_t)k * CSTR + sp * LDIM + l];
        else if (k < 512) val = pos[(size_t)(k - 256) * CSTR + sp * LDIM + l];
        else              val = glob[l * CDIM + (k - 512)];
        sA[i][kk] = val;
    }
    __syncthreads();
    int j = t;
    float acc[16];
#pragma unroll
    for (int i = 0; i < 16; ++i) acc[i] = 0.f;
#pragma unroll
    for (int kk = 0; kk < G1_KB; ++kk) {
        float wv = W1[(size_t)(k0 + kk) * 256 + j];
#pragma unroll
        for (int i = 0; i < 16; ++i) acc[i] = fmaf(sA[i][kk], wv, acc[i]);
    }
#pragma unroll
    for (int i = 0; i < 16; ++i)
        p1[((size_t)(ks * 256 + mt * 16 + i)) * 256 + j] = acc[i];
}

// ---- 4. h1[m][j] = relu(b1[j] + sum_64 p1[s][m][j]) ----
__global__ void k_h1red(const float* __restrict__ p1, const float* __restrict__ b1,
                        float* __restrict__ h1) {
    int m = blockIdx.x, j = threadIdx.x;
    float v = b1[j];
#pragma unroll 8
    for (int s = 0; s < G1_KS; ++s) v += p1[((size_t)(s * 256 + m)) * 256 + j];
    h1[m * 256 + j] = fmaxf(v, 0.f);
}

// ---- 5. GEMM2 partials: 1024 blocks = 32 mt(8 rows) x 32 ks(KB=8) ----
__global__ void k_gemm2(const float* __restrict__ h1, const float* __restrict__ W2,
                        float* __restrict__ p2) {
    __shared__ float sH[8][G2_KB];
    int mt = blockIdx.x >> 5, ks = blockIdx.x & 31;
    int k0 = ks * G2_KB, m0 = mt * 8;
    int t = threadIdx.x;
    if (t < 64) {
        int i = t >> 3, kk = t & 7;
        sH[i][kk] = h1[(m0 + i) * 256 + k0 + kk];
    }
    __syncthreads();
    int j = t;
    float acc[8];
#pragma unroll
    for (int i = 0; i < 8; ++i) acc[i] = 0.f;
#pragma unroll
    for (int kk = 0; kk < G2_KB; ++kk) {
        float wv = W2[(size_t)(k0 + kk) * 256 + j];
#pragma unroll
        for (int i = 0; i < 8; ++i) acc[i] = fmaf(sH[i][kk], wv, acc[i]);
    }
#pragma unroll
    for (int i = 0; i < 8; ++i)
        p2[((size_t)(ks * 256 + m0 + i)) * 256 + j] = acc[i];
}

// ---- 6. Heads + trilinear sample + LayerNorm + scatter-write ----
__global__ void k_heads_sample(const float* __restrict__ feat,
                               const float* __restrict__ p2, const float* __restrict__ b2,
                               const float* __restrict__ Wn, const float* __restrict__ bn,
                               const float* __restrict__ Woff, const float* __restrict__ boff,
                               const float* __restrict__ Ww, const float* __restrict__ bw,
                               const float* __restrict__ gamma, const float* __restrict__ beta,
                               float* __restrict__ out, float* __restrict__ next_out) {
    __shared__ float s_samp[4][3];
    __shared__ float s_wo[4];
    __shared__ float s_w[32];
    __shared__ int   s_o[32];
    __shared__ float red1[4], red2[4], redn[3][4];

    int m = blockIdx.x, l = m >> 6, n = m & 63;
    int j = threadIdx.x, o = j >> 6, r = j & 63;

    float v = b2[j];
#pragma unroll 8
    for (int s = 0; s < G2_KS; ++s) v += p2[((size_t)(s * 256 + m)) * 256 + j];
    v = fmaxf(v, 0.f);              // osrc[m][j]

    // nxt = osrc @ Wn (full-256 reduction via per-wave partials)
    float pn0 = wave_sum64(v * Wn[j * 3 + 0]);
    float pn1 = wave_sum64(v * Wn[j * 3 + 1]);
    float pn2 = wave_sum64(v * Wn[j * 3 + 2]);
    if (r == 0) { redn[0][o] = pn0; redn[1][o] = pn1; redn[2][o] = pn2; }

    // per-o heads (d=64): offset and w_o
    float po0 = wave_sum64(v * Woff[r * 3 + 0]);
    float po1 = wave_sum64(v * Woff[r * 3 + 1]);
    float po2 = wave_sum64(v * Woff[r * 3 + 2]);
    float z0  = wave_sum64(v * Ww[r * 2 + 0]);
    float z1  = wave_sum64(v * Ww[r * 2 + 1]);

    float tn = (float)c_ti[n >> 4] / 7.f;
    float hn = (float)c_hw[(n >> 2) & 3] / 31.f;
    float wn = (float)c_hw[n & 3] / 31.f;
    float lg0 = logf(tn / (1.f - tn));
    float lg1 = logf(hn / (1.f - hn));
    float lg2 = logf(wn / (1.f - wn));

    if (r == 0) {
        s_samp[o][0] = sigm(lg0 + po0 + boff[0]) * 2.f - 1.f;
        s_samp[o][1] = sigm(lg1 + po1 + boff[1]) * 2.f - 1.f;
        s_samp[o][2] = sigm(lg2 + po2 + boff[2]) * 2.f - 1.f;
        s_wo[o] = 1.f / (1.f + expf((z0 + bw[0]) - (z1 + bw[1])));   // softmax[...,1]
    }
    __syncthreads();

    if (j == 0) {
        float t0 = redn[0][0] + redn[0][1] + redn[0][2] + redn[0][3];
        float t1 = redn[1][0] + redn[1][1] + redn[1][2] + redn[1][3];
        float t2 = redn[2][0] + redn[2][1] + redn[2][2] + redn[2][3];
        float d0 = rintf(sigm(lg0 + t0 + bn[0]) * 7.f);
        float d1 = rintf(sigm(lg1 + t1 + bn[1]) * 31.f);
        float d2 = rintf(sigm(lg2 + t2 + bn[2]) * 31.f);
        next_out[m] = 1024.f * d0 + 32.f * d1 + d2;   // H*W*d0 + W*d1 + d2
    }

    if (j < 4) {
        int oo = j;
        float wv = s_wo[oo];
        float g0 = s_samp[oo][0], g1 = s_samp[oo][1], g2 = s_samp[oo][2];
        // reference grid_sample: ch0 -> x over W, ch1 -> y over H, ch2 -> z over D(=T)
        float ix = ((g0 + 1.f) * 32.f - 1.f) * 0.5f;
        float iy = ((g1 + 1.f) * 32.f - 1.f) * 0.5f;
        float iz = ((g2 + 1.f) * 8.f  - 1.f) * 0.5f;
        float x0f = floorf(ix), y0f = floorf(iy), z0f = floorf(iz);
        float fx = ix - x0f, fy = iy - y0f, fz = iz - z0f;
        int x0 = (int)x0f, y0 = (int)y0f, z0 = (int)z0f;
#pragma unroll
        for (int k = 0; k < 8; ++k) {
            int dx = k & 1, dy = (k >> 1) & 1, dz = k >> 2;
            int xi = x0 + dx, yi = y0 + dy, zi = z0 + dz;
            float w = (dx ? fx : 1.f - fx) * (dy ? fy : 1.f - fy) * (dz ? fz : 1.f - fz);
            bool valid = (xi >= 0) && (xi < WDIM) && (yi >= 0) && (yi < HDIM) && (zi >= 0) && (zi < TDIM);
            int xc = min(max(xi, 0), WDIM - 1);
            int yc = min(max(yi, 0), HDIM - 1);
            int zc = min(max(zi, 0), TDIM - 1);
            s_w[oo * 8 + k] = valid ? w * wv : 0.f;
            s_o[oo * 8 + k] = ((zc * HDIM + yc) * WDIM + xc) * LDIM + l;
        }
    }
    __syncthreads();

    int c = j;
    const float* fc = feat + (size_t)c * CSTR;
    int sp = (c_ti[n >> 4] * HDIM + c_hw[(n >> 2) & 3]) * WDIM + c_hw[n & 3];
    float acc = fc[sp * LDIM + l];          // features + wsf at this site
#pragma unroll
    for (int k = 0; k < 32; ++k) acc += s_w[k] * fc[s_o[k]];

    // LayerNorm over C=256
    float s1 = acc, s2 = acc * acc;
#pragma unroll
    for (int d = 32; d > 0; d >>= 1) { s1 += __shfl_xor(s1, d, 64); s2 += __shfl_xor(s2, d, 64); }
    int wid = j >> 6;
    if ((j & 63) == 0) { red1[wid] = s1; red2[wid] = s2; }
    __syncthreads();
    float tot  = red1[0] + red1[1] + red1[2] + red1[3];
    float totq = red2[0] + red2[1] + red2[2] + red2[3];
    float mu = tot * (1.f / 256.f);
    float var = fmaxf(totq * (1.f / 256.f) - mu * mu, 0.f);
    float y = (acc - mu) * rsqrtf(var + 1e-5f) * gamma[c] + beta[c];
    out[(size_t)c * CSTR + sp * LDIM + l] = y;
}

extern "C" void kernel_launch(void* const* d_in, const int* in_sizes, int n_in,
                              void* d_out, int out_size, void* d_ws, size_t ws_size,
                              hipStream_t stream) {
    const float* feat = (const float*)d_in[0];
    const float* pos  = (const float*)d_in[1];
    const float* W1   = (const float*)d_in[2];
    const float* b1   = (const float*)d_in[3];
    const float* W2   = (const float*)d_in[4];
    const float* b2   = (const float*)d_in[5];
    const float* Wn   = (const float*)d_in[6];
    const float* bn   = (const float*)d_in[7];
    // d_in[8]=Wl, d_in[9]=bl provably unused (softmax rows sum to 1)
    const float* Woff = (const float*)d_in[10];
    const float* boff = (const float*)d_in[11];
    const float* Ww   = (const float*)d_in[12];
    const float* bw   = (const float*)d_in[13];
    const float* gamma= (const float*)d_in[14];
    const float* beta = (const float*)d_in[15];
    float* out = (float*)d_out;
    float* next_out = out + OUT0_SIZE;

    float* ws    = (float*)d_ws;
    float4* partF= (float4*)ws;                  // 2048 float4 = 8192 floats
    float* glob  = ws + 8192;                    // 1024
    float* h1    = glob + 1024;                  // 65536
    float* p1    = h1 + 65536;                   // 64*65536 = 4194304
    float* p2    = p1 + (size_t)G1_KS * 65536;   // 32*65536 = 2097152

    k_fill_part<<<2048, 256, 0, stream>>>(feat, beta, out, partF);
    k_globred<<<4, 256, 0, stream>>>(partF, glob);
    k_gemm1<<<16 * G1_KS, 256, 0, stream>>>(feat, pos, glob, W1, p1);
    k_h1red<<<256, 256, 0, stream>>>(p1, b1, h1);
    k_gemm2<<<32 * G2_KS, 256, 0, stream>>>(h1, W2, p2);
    k_heads_sample<<<256, 256, 0, stream>>>(feat, p2, b2, Wn, bn, Woff, boff, Ww, bw,
                                            gamma, beta, out, next_out);
}

// Round 5
// 154.882 us; speedup vs baseline: 1.8242x; 1.0297x over previous
//
#include <hip/hip_runtime.h>
#include <math.h>

// Problem constants (B=1, C=256, T=8, H=32, W=32, L=4, NUM_PTS=4, N_OFF=4)
#define CDIM 256
#define TDIM 8
#define HDIM 32
#define WDIM 32
#define LDIM 4
#define THW 8192
#define CSTR 32768            // T*H*W*L, per-channel stride in features
#define NS 64                 // NUM_PTS^3
#define OUT0_SIZE 8388608     // C*T*H*W*L

// uniform_flat_indices axes for T=8 / H=W=32, n=4 (round(linspace(hop/2, D-1-hop/2, 4)))
__device__ __constant__ int c_ti[4] = {1, 3, 4, 6};
__device__ __constant__ int c_hw[4] = {4, 12, 19, 27};

__device__ __forceinline__ float sigm(float x) { return 1.f / (1.f + expf(-x)); }

__device__ __forceinline__ float wave_sum64(float x) {
#pragma unroll
    for (int s = 32; s > 0; s >>= 1) x += __shfl_xor(x, s, 64);
    return x;
}

// ---- 1. Fill out with beta[c] + per-block partial feature sums (8 blocks/channel) ----
__global__ void __launch_bounds__(256)
k_fill_part(const float* __restrict__ feat, const float* __restrict__ beta,
            float* __restrict__ out, float4* __restrict__ partF) {
    int c = blockIdx.x >> 3, part = blockIdx.x & 7;
    float bv = beta[c];
    float4 bf = make_float4(bv, bv, bv, bv);
    const float4* f = (const float4*)(feat + (size_t)c * CSTR) + part * 1024;
    float4* o = (float4*)(out + (size_t)c * CSTR) + part * 1024;
    float4 a = make_float4(0.f, 0.f, 0.f, 0.f);
#pragma unroll
    for (int it = 0; it < 4; ++it) {
        int i = it * 256 + threadIdx.x;
        float4 v = f[i];
        o[i] = bf;
        a.x += v.x; a.y += v.y; a.z += v.z; a.w += v.w;
    }
#pragma unroll
    for (int s = 32; s > 0; s >>= 1) {
        a.x += __shfl_xor(a.x, s, 64);
        a.y += __shfl_xor(a.y, s, 64);
        a.z += __shfl_xor(a.z, s, 64);
        a.w += __shfl_xor(a.w, s, 64);
    }
    __shared__ float4 sw[4];
    if ((threadIdx.x & 63) == 0) sw[threadIdx.x >> 6] = a;
    __syncthreads();
    if (threadIdx.x == 0) {
        float4 r;
        r.x = sw[0].x + sw[1].x + sw[2].x + sw[3].x;
        r.y = sw[0].y + sw[1].y + sw[2].y + sw[3].y;
        r.z = sw[0].z + sw[1].z + sw[2].z + sw[3].z;
        r.w = sw[0].w + sw[1].w + sw[2].w + sw[3].w;
        partF[blockIdx.x] = r;
    }
}

// ---- 2. Build k-major A matrix in1T[768][256]: rows 0..255 feat, 256..511 pos, 512..767 glob ----
__global__ void __launch_bounds__(256)
k_gather(const float* __restrict__ feat, const float* __restrict__ pos,
         const float4* __restrict__ partF, float* __restrict__ in1T) {
    int m = blockIdx.x, l = m >> 6, n = m & 63;
    int sp = (c_ti[n >> 4] * HDIM + c_hw[(n >> 2) & 3]) * WDIM + c_hw[n & 3];
    int t = threadIdx.x;
    in1T[(size_t)t * 256 + m] = feat[(size_t)t * CSTR + sp * LDIM + l];
    in1T[(size_t)(256 + t) * 256 + m] = pos[(size_t)t * CSTR + sp * LDIM + l];
    float s = 0.f;
#pragma unroll
    for (int p = 0; p < 8; ++p) {
        float4 v = partF[t * 8 + p];
        s += (l == 0) ? v.x : (l == 1) ? v.y : (l == 2) ? v.z : v.w;
    }
    in1T[(size_t)(512 + t) * 256 + m] = s * (1.f / 8192.f);
}

// ---- 3/4. In-block split-K GEMM: out = relu(bias + A(in k-major) @ W) ----
// Block: 16 m-rows x 16 j-cols. Thread: (j8 = t&7 -> 2 cols, kq = t>>3 -> K-chunk stride-32).
// A read from global (L2-resident), K-partials reduced via padded LDS.
// WRITE_T = 0: write out[m][j] (m-major). WRITE_T = 1: write outT[j][m] (k-major for next GEMM).
template <int KITER, int WRITE_T>
__global__ void __launch_bounds__(256)
k_gemm(const float* __restrict__ AT, const float* __restrict__ Wt,
       const float* __restrict__ bias, float* __restrict__ outp) {
    __shared__ float sAcc[256][33];
    int mt = blockIdx.x >> 4, jt = blockIdx.x & 15;
    int m0 = mt * 16, j0 = jt * 16;
    int t = threadIdx.x;
    int j8 = t & 7, kq = t >> 3;            // kq in [0,32)
    int j = j0 + j8 * 2;
    float acc0[16], acc1[16];
#pragma unroll
    for (int i = 0; i < 16; ++i) { acc0[i] = 0.f; acc1[i] = 0.f; }
#pragma unroll 4
    for (int kk = 0; kk < KITER; ++kk) {
        int k = kq + (kk << 5);             // interleaved K-chunks
        const float4* ap = (const float4*)(AT + (size_t)k * 256 + m0);
        float av[16];
        ((float4*)av)[0] = ap[0];
        ((float4*)av)[1] = ap[1];
        ((float4*)av)[2] = ap[2];
        ((float4*)av)[3] = ap[3];
        float2 w = *(const float2*)(Wt + (size_t)k * 256 + j);
#pragma unroll
        for (int i = 0; i < 16; ++i) {
            acc0[i] = fmaf(av[i], w.x, acc0[i]);
            acc1[i] = fmaf(av[i], w.y, acc1[i]);
        }
    }
#pragma unroll
    for (int i = 0; i < 16; ++i) {
        sAcc[i * 16 + j8 * 2 + 0][kq] = acc0[i];
        sAcc[i * 16 + j8 * 2 + 1][kq] = acc1[i];
    }
    __syncthreads();
    // thread t -> output o = t: i = t>>4 (m-offset), jj = t&15 (j-offset)
    int i = t >> 4, jj = t & 15;
    float v = bias[j0 + jj];
#pragma unroll
    for (int q = 0; q < 32; ++q) v += sAcc[t][q];
    v = fmaxf(v, 0.f);
    if (WRITE_T)
        outp[(size_t)(j0 + jj) * 256 + m0 + i] = v;
    else
        outp[(size_t)(m0 + i) * 256 + j0 + jj] = v;
}

// ---- 5. Heads + trilinear sample + LayerNorm + scatter-write ----
__global__ void __launch_bounds__(256)
k_heads_sample(const float* __restrict__ feat, const float* __restrict__ osrc,
               const float* __restrict__ Wn, const float* __restrict__ bn,
               const float* __restrict__ Woff, const float* __restrict__ boff,
               const float* __restrict__ Ww, const float* __restrict__ bw,
               const float* __restrict__ gamma, const float* __restrict__ beta,
               float* __restrict__ out, float* __restrict__ next_out) {
    __shared__ float s_samp[4][3];
    __shared__ float s_wo[4];
    __shared__ float s_w[32];
    __shared__ int   s_o[32];
    __shared__ float red1[4], red2[4], redn[3][4];

    int m = blockIdx.x, l = m >> 6, n = m & 63;
    int j = threadIdx.x, o = j >> 6, r = j & 63;

    float v = osrc[(size_t)m * 256 + j];

    // nxt = osrc @ Wn (full-256 reduction via per-wave partials)
    float pn0 = wave_sum64(v * Wn[j * 3 + 0]);
    float pn1 = wave_sum64(v * Wn[j * 3 + 1]);
    float pn2 = wave_sum64(v * Wn[j * 3 + 2]);
    if (r == 0) { redn[0][o] = pn0; redn[1][o] = pn1; redn[2][o] = pn2; }

    // per-o heads (d=64): offset and w_o
    float po0 = wave_sum64(v * Woff[r * 3 + 0]);
    float po1 = wave_sum64(v * Woff[r * 3 + 1]);
    float po2 = wave_sum64(v * Woff[r * 3 + 2]);
    float z0  = wave_sum64(v * Ww[r * 2 + 0]);
    float z1  = wave_sum64(v * Ww[r * 2 + 1]);

    float tn = (float)c_ti[n >> 4] / 7.f;
    float hn = (float)c_hw[(n >> 2) & 3] / 31.f;
    float wn = (float)c_hw[n & 3] / 31.f;
    float lg0 = logf(tn / (1.f - tn));
    float lg1 = logf(hn / (1.f - hn));
    float lg2 = logf(wn / (1.f - wn));

    if (r == 0) {
        s_samp[o][0] = sigm(lg0 + po0 + boff[0]) * 2.f - 1.f;
        s_samp[o][1] = sigm(lg1 + po1 + boff[1]) * 2.f - 1.f;
        s_samp[o][2] = sigm(lg2 + po2 + boff[2]) * 2.f - 1.f;
        s_wo[o] = 1.f / (1.f + expf((z0 + bw[0]) - (z1 + bw[1])));   // softmax[...,1]
    }
    __syncthreads();

    if (j == 0) {
        float t0 = redn[0][0] + redn[0][1] + redn[0][2] + redn[0][3];
        float t1 = redn[1][0] + redn[1][1] + redn[1][2] + redn[1][3];
        float t2 = redn[2][0] + redn[2][1] + redn[2][2] + redn[2][3];
        float d0 = rintf(sigm(lg0 + t0 + bn[0]) * 7.f);
        float d1 = rintf(sigm(lg1 + t1 + bn[1]) * 31.f);
        float d2 = rintf(sigm(lg2 + t2 + bn[2]) * 31.f);
        next_out[m] = 1024.f * d0 + 32.f * d1 + d2;   // H*W*d0 + W*d1 + d2
    }

    if (j < 4) {
        int oo = j;
        float wv = s_wo[oo];
        float g0 = s_samp[oo][0], g1 = s_samp[oo][1], g2 = s_samp[oo][2];
        // reference grid_sample: ch0 -> x over W, ch1 -> y over H, ch2 -> z over D(=T)
        float ix = ((g0 + 1.f) * 32.f - 1.f) * 0.5f;
        float iy = ((g1 + 1.f) * 32.f - 1.f) * 0.5f;
        float iz = ((g2 + 1.f) * 8.f  - 1.f) * 0.5f;
        float x0f = floorf(ix), y0f = floorf(iy), z0f = floorf(iz);
        float fx = ix - x0f, fy = iy - y0f, fz = iz - z0f;
        int x0 = (int)x0f, y0 = (int)y0f, z0 = (int)z0f;
#pragma unroll
        for (int k = 0; k < 8; ++k) {
            int dx = k & 1, dy = (k >> 1) & 1, dz = k >> 2;
            int xi = x0 + dx, yi = y0 + dy, zi = z0 + dz;
            float w = (dx ? fx : 1.f - fx) * (dy ? fy : 1.f - fy) * (dz ? fz : 1.f - fz);
            bool valid = (xi >= 0) && (xi < WDIM) && (yi >= 0) && (yi < HDIM) && (zi >= 0) && (zi < TDIM);
            int xc = min(max(xi, 0), WDIM - 1);
            int yc = min(max(yi, 0), HDIM - 1);
            int zc = min(max(zi, 0), TDIM - 1);
            s_w[oo * 8 + k] = valid ? w * wv : 0.f;
            s_o[oo * 8 + k] = ((zc * HDIM + yc) * WDIM + xc) * LDIM + l;
        }
    }
    __syncthreads();

    int c = j;
    const float* fc = feat + (size_t)c * CSTR;
    int sp = (c_ti[n >> 4] * HDIM + c_hw[(n >> 2) & 3]) * WDIM + c_hw[n & 3];
    float acc = fc[sp * LDIM + l];          // features + wsf at this site
#pragma unroll
    for (int k = 0; k < 32; ++k) acc += s_w[k] * fc[s_o[k]];

    // LayerNorm over C=256
    float s1 = acc, s2 = acc * acc;
#pragma unroll
    for (int d = 32; d > 0; d >>= 1) { s1 += __shfl_xor(s1, d, 64); s2 += __shfl_xor(s2, d, 64); }
    int wid = j >> 6;
    if ((j & 63) == 0) { red1[wid] = s1; red2[wid] = s2; }
    __syncthreads();
    float tot  = red1[0] + red1[1] + red1[2] + red1[3];
    float totq = red2[0] + red2[1] + red2[2] + red2[3];
    float mu = tot * (1.f / 256.f);
    float var = fmaxf(totq * (1.f / 256.f) - mu * mu, 0.f);
    float y = (acc - mu) * rsqrtf(var + 1e-5f) * gamma[c] + beta[c];
    out[(size_t)c * CSTR + sp * LDIM + l] = y;
}

extern "C" void kernel_launch(void* const* d_in, const int* in_sizes, int n_in,
                              void* d_out, int out_size, void* d_ws, size_t ws_size,
                              hipStream_t stream) {
    const float* feat = (const float*)d_in[0];
    const float* pos  = (const float*)d_in[1];
    const float* W1   = (const float*)d_in[2];
    const float* b1   = (const float*)d_in[3];
    const float* W2   = (const float*)d_in[4];
    const float* b2   = (const float*)d_in[5];
    const float* Wn   = (const float*)d_in[6];
    const float* bn   = (const float*)d_in[7];
    // d_in[8]=Wl, d_in[9]=bl provably unused (softmax rows sum to 1)
    const float* Woff = (const float*)d_in[10];
    const float* boff = (const float*)d_in[11];
    const float* Ww   = (const float*)d_in[12];
    const float* bw   = (const float*)d_in[13];
    const float* gamma= (const float*)d_in[14];
    const float* beta = (const float*)d_in[15];
    float* out = (float*)d_out;
    float* next_out = out + OUT0_SIZE;

    float* ws    = (float*)d_ws;
    float4* partF= (float4*)ws;             // 2048 float4 = 8192 floats
    float* in1T  = ws + 8192;               // 768*256 = 196608
    float* h1T   = in1T + 196608;           // 65536 (k-major: [j][m])
    float* osrc  = h1T + 65536;             // 65536 (m-major: [m][j])

    k_fill_part<<<2048, 256, 0, stream>>>(feat, beta, out, partF);
    k_gather<<<256, 256, 0, stream>>>(feat, pos, partF, in1T);
    k_gemm<24, 1><<<256, 256, 0, stream>>>(in1T, W1, b1, h1T);   // GEMM1: K=768 -> h1T (k-major)
    k_gemm<8, 0><<<256, 256, 0, stream>>>(h1T, W2, b2, osrc);    // GEMM2: K=256 -> osrc (m-major)
    k_heads_sample<<<256, 256, 0, stream>>>(feat, osrc, Wn, bn, Woff, boff, Ww, bw,
                                            gamma, beta, out, next_out);
}